// Round 2
// baseline (247.338 us; speedup 1.0000x reference)
//
#include <hip/hip_runtime.h>
#include <cstdint>

#define GH 10
#define GW 10

// Load 5 consecutive rows (50 floats) with 15 independent vector loads.
__device__ __forceinline__ void load5(const float* __restrict__ rp, float* v) {
#pragma unroll
    for (int i = 0; i < 5; ++i) {
        const float4 a = *(const float4*)(rp + i * 10);
        const float4 b = *(const float4*)(rp + i * 10 + 4);
        const float2 c = *(const float2*)(rp + i * 10 + 8);
        v[i*10+0]=a.x; v[i*10+1]=a.y; v[i*10+2]=a.z; v[i*10+3]=a.w;
        v[i*10+4]=b.x; v[i*10+5]=b.y; v[i*10+6]=b.z; v[i*10+7]=b.w;
        v[i*10+8]=c.x; v[i*10+9]=c.y;
    }
}

// Pass 1 over 5 rows: accumulate sum_all, sc = sum x*(ady+adx), boxSum,
// and the round(x)==1 bitmask word (rows at bits 0,10,20,30,40).
template<int Y0>
__device__ __forceinline__ void pass1_chunk(const float* v, int p0y, int p1y, int dy0,
                                            const float* adxf, const float* inboxf,
                                            float& sum_all, float& sc, float& boxSum,
                                            uint64_t& mword)
{
#pragma unroll
    for (int i = 0; i < 5; ++i) {
        const int y = Y0 + i;
        const float* vv = v + i * 10;
        const float rowacc = ((vv[0]+vv[1])+(vv[2]+vv[3])) +
                             ((vv[4]+vv[5])+(vv[6]+vv[7])) + (vv[8]+vv[9]);
        sum_all += rowacc;
        const int ay = abs(y - p0y) + abs(y - p1y) - dy0;
        sc = fmaf((float)ay, rowacc, sc);
        float boxrow = 0.f;
        uint32_t rm = 0u;
#pragma unroll
        for (int x = 0; x < 10; ++x) {
            const float xv = vv[x];
            sc = fmaf(adxf[x], xv, sc);
            boxrow = fmaf(inboxf[x], xv, boxrow);
            rm |= (xv > 0.5f) ? (1u << x) : 0u;
        }
        boxSum += (ay == 0) ? boxrow : 0.f;
        mword |= (uint64_t)rm << (10 * i);
    }
}

// Pass 2 over 5 rows: S_T += value[y][x] where transposed-cluster bit (x*10+y) set.
template<int Y0>
__device__ __forceinline__ float pass2_chunk(const float* v, uint64_t clo, uint64_t chi)
{
    float s = 0.f;
#pragma unroll
    for (int i = 0; i < 5; ++i) {
        const int y = Y0 + i;
        const float* vv = v + i * 10;
#pragma unroll
        for (int x = 0; x < 10; ++x) {
            const int b = x * 10 + y;   // cluster.T membership: cluster[x][y]
            const uint32_t bit = (b < 50) ? (uint32_t)((clo >> b) & 1ull)
                                          : (uint32_t)((chi >> (b - 50)) & 1ull);
            s = fmaf((float)bit, vv[x], s);
        }
    }
    return s;
}

__global__ __launch_bounds__(256, 4) void custom_loss_kernel(
    const float* __restrict__ result,
    const int* __restrict__ points,
    float* __restrict__ out,
    int B)
{
    const int t = blockIdx.x * blockDim.x + threadIdx.x;
    float loss = 0.f;
    if (t < B) {
        const float* __restrict__ r = result + (size_t)t * 100;
        const int4 p = ((const int4*)points)[t];
        const int p0y = p.x, p0x = p.y, p1y = p.z, p1x = p.w;
        const int dy0 = abs(p0y - p1y), dx0 = abs(p0x - p1x);
        const int base = dy0 + dx0;
        // direct loads, issued early; latency hidden under pass 1
        const float rs = r[p0y * GW + p0x];
        const float re = r[p1y * GW + p1x];

        float adxf[10], inboxf[10];
#pragma unroll
        for (int x = 0; x < 10; ++x) {
            const int a = abs(x - p0x) + abs(x - p1x) - dx0;
            adxf[x] = (float)a;
            inboxf[x] = (a == 0) ? 1.f : 0.f;
        }

        float sum_all = 0.f, sc = 0.f, boxSum = 0.f;
        uint64_t mlo = 0, mhi = 0;

        float vA[50], vB[50];
        load5(r, vA);
        pass1_chunk<0>(vA, p0y, p1y, dy0, adxf, inboxf, sum_all, sc, boxSum, mlo);
        load5(r + 50, vB);
        pass1_chunk<5>(vB, p0y, p1y, dy0, adxf, inboxf, sum_all, sc, boxSum, mhi);
        // vB stays live through the flood fill for pass 2; vA is reloaded after.

        // ---- 8-connected flood fill on a 100-bit bitboard (rows of 10 bits) ----
        const uint64_t M50 = (1ull << 50) - 1;
        const uint64_t C0  = 0x10040100401ull;        // column-0 bit of each of 5 rows
        const uint64_t NC0 = M50 & ~C0;               // clear col0 after <<1
        const uint64_t NC9 = M50 & ~(C0 << 9);        // clear col9 after >>1
        const int idx0 = p0y * GW + p0x;
        uint64_t clo = 0, chi = 0;
        if (idx0 < 50) clo = 1ull << idx0; else chi = 1ull << (idx0 - 50);
#pragma unroll 1
        for (int it = 0; it < GH + GW; ++it) {        // monotone: early exit == fixed 20
            const uint64_t hlo = clo | ((clo << 1) & NC0) | ((clo >> 1) & NC9);
            const uint64_t hhi = chi | ((chi << 1) & NC0) | ((chi >> 1) & NC9);
            uint64_t nlo = (hlo | (hlo << 10) | (hlo >> 10) | ((hhi & 0x3FFull) << 40)) & mlo;
            uint64_t nhi = (hhi | (hhi << 10) | (hhi >> 10) | (hlo >> 40)) & mhi;
            nlo |= clo; nhi |= chi;
            if (nlo == clo && nhi == chi) break;
            clo = nlo; chi = nhi;
        }

        const int K = __popcll(clo) + __popcll(chi);

        // reload rows 0..4 now — latency overlaps the argmin below
        load5(r, vA);

        // ---- argmin over cluster cells of dist-to-end, first-flat-index ties ----
        int bestd = 1000, bidx = 0;
#pragma unroll
        for (int y = 0; y < GH; ++y) {
            const uint32_t rb = (uint32_t)((y < 5 ? (clo >> (10 * y))
                                                  : (chi >> (10 * (y - 5)))) & 0x3FFull);
            const uint32_t left  = rb & ((2u << p1x) - 1);   // cols 0..p1x
            const uint32_t right = rb >> p1x;                // bit0 = col p1x
            const int dl = left  ? (p1x - (31 - __builtin_clz(left))) : 1000;
            const int dr = right ? __builtin_ctz(right) : 1000;
            int dx, xx;
            if (dl <= dr) { dx = dl; xx = p1x - dl; }        // tie -> smaller col
            else          { dx = dr; xx = p1x + dr; }
            const int d = abs(y - p1y) + dx;
            if (rb && d < bestd) { bestd = d; bidx = y * GW + xx; } // tie -> smaller row
        }

        const bool better = bestd < base;
        const int ny = better ? bidx / 10 : p0y;
        const int nx = better ? bidx % 10 : p0x;
        const int gap = min(base, bestd);

        int by = ny, bx = nx, bg = gap;
        const int oy = p1y - ny, ox = p1x - nx;
        auto upd = [&](bool cond, int cy, int cx) {
            const int d = abs(cy - p1y) + abs(cx - p1x);
            if (cond && (d < bg)) { by = cy; bx = cx; bg = d; }
        };
        upd(ox < 0,                     ny,     nx - 1);
        upd((ox < 0) && (ny != 0),      ny - 1, nx - 1);
        upd((ox < 0) && (ny != GH - 1), ny + 1, nx - 1);
        upd(ox > 0,                     ny,     nx + 1);
        upd((ox > 0) && (ny != 0),      ny - 1, nx + 1);
        upd((ox > 0) && (ny != GH - 1), ny + 1, nx + 1);
        upd(oy < 0,                     ny - 1, nx);
        upd(oy > 0,                     ny + 1, nx);
        const int ncy = min(max(by, 0), GH - 1);
        const int ncx = min(max(bx, 0), GW - 1);
        const float rn = r[ncy * GW + ncx];

        // ---- pass 2: transposed-cluster weighted sum ----
        const float S_T = pass2_chunk<0>(vA, clo, chi) + pass2_chunk<5>(vB, clo, chi);

        const float csf = (float)K;
        const float nboxf = (float)((dy0 + 1) * (dx0 + 1));
        const float loss_start = (2.f - (rs + re)) * 1000.f;
        const float lon = 5.f * csf + 15.f * sum_all - 20.f * S_T;    // lonelyness
        const float single_cell = 0.5f * sc + 20.f * (nboxf - boxSum);
        const float cpen = 12.f * csf * S_T;                          // cluster-size pen
        const float gap_pen = (float)gap * 300.f * (1.f - rn);
        loss = loss_start + lon + single_cell + cpen + gap_pen;
    }

    // ---- block reduction: wave shuffle -> LDS -> one atomic per block ----
#pragma unroll
    for (int off = 32; off > 0; off >>= 1)
        loss += __shfl_down(loss, off);
    __shared__ float wsum[4];
    const int lane = threadIdx.x & 63;
    const int wid = threadIdx.x >> 6;
    if (lane == 0) wsum[wid] = loss;
    __syncthreads();
    if (threadIdx.x == 0)
        atomicAdd(out, wsum[0] + wsum[1] + wsum[2] + wsum[3]);
}

extern "C" void kernel_launch(void* const* d_in, const int* in_sizes, int n_in,
                              void* d_out, int out_size, void* d_ws, size_t ws_size,
                              hipStream_t stream)
{
    const float* result = (const float*)d_in[0];
    const int* points   = (const int*)d_in[1];
    float* out = (float*)d_out;
    const int B = in_sizes[0] / 100;
    hipMemsetAsync(out, 0, sizeof(float), stream);   // harness poisons d_out with 0xAA
    const int block = 256;
    const int grid = (B + block - 1) / block;
    custom_loss_kernel<<<grid, block, 0, stream>>>(result, points, out, B);
}

// Round 3
// 182.638 us; speedup vs baseline: 1.3543x; 1.3543x over previous
//
#include <hip/hip_runtime.h>
#include <cstdint>

#define GH 10
#define GW 10

__global__ __launch_bounds__(256, 1) void custom_loss_kernel(
    const float* __restrict__ result,
    const int* __restrict__ points,
    float* __restrict__ out,
    int B)
{
    const int t = blockIdx.x * blockDim.x + threadIdx.x;
    float loss = 0.f;
    if (t < B) {
        const float* __restrict__ r = result + (size_t)t * 100;
        const int4 p = ((const int4*)points)[t];
        const int p0y = p.x, p0x = p.y, p1y = p.z, p1x = p.w;
        const int dy0 = abs(p0y - p1y), dx0 = abs(p0x - p1x);
        const int base = dy0 + dx0;
        const int idx0 = p0y * GW + p0x;
        const int idx1 = p1y * GW + p1x;
        // independent point loads, issued early; latency hidden under pass 1
        const float rs = r[idx0];
        const float re = r[idx1];

        float adxf[10], inboxf[10];
#pragma unroll
        for (int x = 0; x < 10; ++x) {
            const int a = abs(x - p0x) + abs(x - p1x) - dx0;
            adxf[x] = (float)a;
            inboxf[x] = (a == 0) ? 1.f : 0.f;
        }

        // ---- pass 1: stream rows, keep nothing (no register arrays) ----
        float sum_all = 0.f, sc = 0.f, boxSum = 0.f;
        uint64_t mlo = 0, mhi = 0;
#pragma unroll
        for (int y = 0; y < GH; ++y) {
            const float* rp = r + y * 10;
            const float4 a = *(const float4*)(rp);
            const float4 b = *(const float4*)(rp + 4);
            const float2 c = *(const float2*)(rp + 8);
            const float vv[10] = {a.x, a.y, a.z, a.w, b.x, b.y, b.z, b.w, c.x, c.y};
            const float rowacc = ((vv[0]+vv[1])+(vv[2]+vv[3])) +
                                 ((vv[4]+vv[5])+(vv[6]+vv[7])) + (vv[8]+vv[9]);
            sum_all += rowacc;
            const int ay = abs(y - p0y) + abs(y - p1y) - dy0;
            sc = fmaf((float)ay, rowacc, sc);
            float boxrow = 0.f;
            uint32_t rm = 0u;
#pragma unroll
            for (int x = 0; x < 10; ++x) {
                const float xv = vv[x];
                sc = fmaf(adxf[x], xv, sc);
                boxrow = fmaf(inboxf[x], xv, boxrow);
                // jnp.round is half-to-even: for x in [0,1), round==1 <=> x>0.5
                rm |= (xv > 0.5f) ? (1u << x) : 0u;
            }
            boxSum += (ay == 0) ? boxrow : 0.f;
            if (y < 5) mlo |= (uint64_t)rm << (10 * y);
            else       mhi |= (uint64_t)rm << (10 * (y - 5));
        }

        // ---- 8-connected flood fill on a 100-bit bitboard (rows of 10 bits) ----
        const uint64_t M50 = (1ull << 50) - 1;
        const uint64_t C0  = 0x10040100401ull;        // column-0 bit of each of 5 rows
        const uint64_t NC0 = M50 & ~C0;               // clear col0 after <<1
        const uint64_t NC9 = M50 & ~(C0 << 9);        // clear col9 after >>1
        uint64_t clo = 0, chi = 0;
        if (idx0 < 50) clo = 1ull << idx0; else chi = 1ull << (idx0 - 50);
#pragma unroll 1
        for (int it = 0; it < GH + GW; ++it) {        // monotone: early exit == fixed 20
            const uint64_t hlo = clo | ((clo << 1) & NC0) | ((clo >> 1) & NC9);
            const uint64_t hhi = chi | ((chi << 1) & NC0) | ((chi >> 1) & NC9);
            uint64_t nlo = (hlo | (hlo << 10) | (hlo >> 10) | ((hhi & 0x3FFull) << 40)) & mlo;
            uint64_t nhi = (hhi | (hhi << 10) | (hhi >> 10) | (hlo >> 40)) & mhi;
            nlo |= clo; nhi |= chi;
            if (nlo == clo && nhi == chi) break;
            clo = nlo; chi = nhi;
        }

        const int K = __popcll(clo) + __popcll(chi);

        // ---- pass 2: re-read rows (L2/L3-warm), transposed-cluster weighted sum.
        // Loads are independent of the flood-fill result; placed here so the
        // compiler can batch them while the bit-math consumes them in order.
        float S_T = 0.f;
#pragma unroll
        for (int y = 0; y < GH; ++y) {
            const float* rp = r + y * 10;
            const float4 a = *(const float4*)(rp);
            const float4 b = *(const float4*)(rp + 4);
            const float2 c = *(const float2*)(rp + 8);
            const float vv[10] = {a.x, a.y, a.z, a.w, b.x, b.y, b.z, b.w, c.x, c.y};
#pragma unroll
            for (int x = 0; x < 10; ++x) {
                const int bpos = x * 10 + y;          // in_cl[y][x] = cluster[x][y]
                const uint32_t bit = (bpos < 50) ? (uint32_t)((clo >> bpos) & 1ull)
                                                 : (uint32_t)((chi >> (bpos - 50)) & 1ull);
                S_T = fmaf((float)bit, vv[x], S_T);
            }
        }

        // ---- argmin over cluster cells of dist-to-end, first-flat-index ties ----
        int bestd = 1000, bidx = 0;
#pragma unroll
        for (int y = 0; y < GH; ++y) {
            const uint32_t rb = (uint32_t)((y < 5 ? (clo >> (10 * y))
                                                  : (chi >> (10 * (y - 5)))) & 0x3FFull);
            const uint32_t left  = rb & ((2u << p1x) - 1);   // cols 0..p1x
            const uint32_t right = rb >> p1x;                // bit0 = col p1x
            const int dl = left  ? (p1x - (31 - __builtin_clz(left))) : 1000;
            const int dr = right ? __builtin_ctz(right) : 1000;
            int dx, xx;
            if (dl <= dr) { dx = dl; xx = p1x - dl; }        // tie -> smaller col
            else          { dx = dr; xx = p1x + dr; }
            const int d = abs(y - p1y) + dx;
            if (rb && d < bestd) { bestd = d; bidx = y * GW + xx; } // tie -> smaller row
        }

        const bool better = bestd < base;
        const int ny = better ? bidx / 10 : p0y;
        const int nx = better ? bidx % 10 : p0x;
        const int gap = min(base, bestd);

        int by = ny, bx = nx, bg = gap;
        const int oy = p1y - ny, ox = p1x - nx;
        auto upd = [&](bool cond, int cy, int cx) {
            const int d = abs(cy - p1y) + abs(cx - p1x);
            if (cond && (d < bg)) { by = cy; bx = cx; bg = d; }
        };
        upd(ox < 0,                     ny,     nx - 1);
        upd((ox < 0) && (ny != 0),      ny - 1, nx - 1);
        upd((ox < 0) && (ny != GH - 1), ny + 1, nx - 1);
        upd(ox > 0,                     ny,     nx + 1);
        upd((ox > 0) && (ny != 0),      ny - 1, nx + 1);
        upd((ox > 0) && (ny != GH - 1), ny + 1, nx + 1);
        upd(oy < 0,                     ny - 1, nx);
        upd(oy > 0,                     ny + 1, nx);
        const int ncy = min(max(by, 0), GH - 1);
        const int ncx = min(max(bx, 0), GW - 1);
        const float rn = r[ncy * GW + ncx];              // single dependent load

        const float csf = (float)K;
        const float nboxf = (float)((dy0 + 1) * (dx0 + 1));
        const float loss_start = (2.f - (rs + re)) * 1000.f;
        const float lon = 5.f * csf + 15.f * sum_all - 20.f * S_T;    // lonelyness
        const float single_cell = 0.5f * sc + 20.f * (nboxf - boxSum);
        const float cpen = 12.f * csf * S_T;                          // cluster-size pen
        const float gap_pen = (float)gap * 300.f * (1.f - rn);
        loss = loss_start + lon + single_cell + cpen + gap_pen;
    }

    // ---- block reduction: wave shuffle -> LDS -> one atomic per block ----
#pragma unroll
    for (int off = 32; off > 0; off >>= 1)
        loss += __shfl_down(loss, off);
    __shared__ float wsum[4];
    const int lane = threadIdx.x & 63;
    const int wid = threadIdx.x >> 6;
    if (lane == 0) wsum[wid] = loss;
    __syncthreads();
    if (threadIdx.x == 0)
        atomicAdd(out, wsum[0] + wsum[1] + wsum[2] + wsum[3]);
}

extern "C" void kernel_launch(void* const* d_in, const int* in_sizes, int n_in,
                              void* d_out, int out_size, void* d_ws, size_t ws_size,
                              hipStream_t stream)
{
    const float* result = (const float*)d_in[0];
    const int* points   = (const int*)d_in[1];
    float* out = (float*)d_out;
    const int B = in_sizes[0] / 100;
    hipMemsetAsync(out, 0, sizeof(float), stream);   // harness poisons d_out with 0xAA
    const int block = 256;
    const int grid = (B + block - 1) / block;
    custom_loss_kernel<<<grid, block, 0, stream>>>(result, points, out, B);
}